// Round 1
// baseline (901.559 us; speedup 1.0000x reference)
//
#include <hip/hip_runtime.h>

#define NT   512
#define NBLK 4096   // B/8

// ---- LDS float offsets ----
#define L_W2   0                 // 16384 f: Wd1, later Wd2
#define L_UV   16384             // U: [4][128][9] p-stride 1160 (=4640 f); V at +4640
#define L_VOFF 4640
#define L_X    25664             // phase1: Wm_top[64][64]=4096 ; phase3: Hd1_T[128][68]=8704
#define L_DP   (L_X + 4096)      // dp [4][8][64] = 2048 f
#define L_S    34368             // small consts
#define S_WV   (L_S + 0)         // 64
#define S_BV   (L_S + 64)        // 64
#define S_BD1  (L_S + 128)       // 128
#define S_BD2  (L_S + 256)       // 128
#define S_C0   (L_S + 384)       // 64
#define S_C1   (L_S + 448)       // 64
#define S_WC   (L_S + 512)       // 2048
#define LDS_FLOATS (L_S + 2560)  // 36928 floats = 147712 B

__global__ void frap_setup(const float* __restrict__ Ws0, const float* __restrict__ bs,
                           const float* __restrict__ Wm,  const float* __restrict__ bm,
                           const float* __restrict__ rel, const float* __restrict__ Wr1,
                           const float* __restrict__ br1, const float* __restrict__ Wr2,
                           const float* __restrict__ br2, const float* __restrict__ Wc,
                           float* __restrict__ wsf)
{
    __shared__ float hr1[128];
    const int t = threadIdx.x;  // 128 threads
    if (blockIdx.x == 16) {
        // c0 / c1 : h_s branch folded through Wm bottom half, + bm
        const int s = t >> 6, e = t & 63;
        float acc = bm[e];
        for (int h = 0; h < 64; ++h) {
            float hs = fmaxf((s ? Ws0[h] : 0.0f) + bs[h], 0.0f);
            acc = fmaf(hs, Wm[(64 + h) * 64 + e], acc);
        }
        wsf[2048 + s * 64 + e] = acc;
    } else {
        const int pair = blockIdx.x;  // p*4+q
        float a = br1[t];
        for (int r = 0; r < 32; ++r) a = fmaf(rel[pair * 32 + r], Wr1[r * 128 + t], a);
        hr1[t] = fmaxf(a, 0.0f);
        __syncthreads();
        float a2 = br2[t];
        for (int j = 0; j < 128; ++j) a2 = fmaf(hr1[j], Wr2[j * 128 + t], a2);
        wsf[pair * 128 + t] = fmaxf(a2, 0.0f) * Wc[t];  // wc_eff
    }
}

__global__ __launch_bounds__(NT, 2)
void frap_main(const float* __restrict__ mc_g, const float* __restrict__ oh_g,
               const float* __restrict__ Wv_g, const float* __restrict__ bv_g,
               const float* __restrict__ Wm_g,
               const float* __restrict__ Wd1_g, const float* __restrict__ bd1_g,
               const float* __restrict__ Wd2_g, const float* __restrict__ bd2_g,
               const float* __restrict__ bc_g,
               const float* __restrict__ wsf, float* __restrict__ out)
{
    extern __shared__ float lds[];
    const int t = threadIdx.x;

    // ---- stage constants + Wm_top + Wd1 ----
    if (t < 64) {
        lds[S_WV + t] = Wv_g[t];
        lds[S_BV + t] = bv_g[t];
        lds[S_C0 + t] = wsf[2048 + t];
        lds[S_C1 + t] = wsf[2112 + t];
    } else if (t < 192) {
        lds[S_BD1 + (t - 64)] = bd1_g[t - 64];
    } else if (t < 320) {
        lds[S_BD2 + (t - 192)] = bd2_g[t - 192];
    }
    for (int i = t; i < 2048; i += NT) lds[S_WC + i] = wsf[i];
    for (int i = t; i < 4096; i += NT) lds[L_X + i] = Wm_g[i];  // Wm_top rows 0..63
    for (int i = t * 4; i < 16384; i += NT * 4)
        *(float4*)&lds[L_W2 + i] = *(const float4*)&Wd1_g[i];
    __syncthreads();

    const int b  = t >> 6;         // 0..7
    const int mp = (t >> 4) & 3;   // movement pair = phase index p
    const int ec = t & 15;         // e-chunk of 4
    const int bg = blockIdx.x * 8 + b;

    // ---- phase 1: d_p[p][e] for this block's 8 b ----
    {
        const float mc0 = mc_g[bg * 8 + 2 * mp];
        const float mc1 = mc_g[bg * 8 + 2 * mp + 1];
        const float sv  = oh_g[bg * 4 + mp];
        float a0[4] = {0.f, 0.f, 0.f, 0.f};
        float a1[4] = {0.f, 0.f, 0.f, 0.f};
        for (int h4 = 0; h4 < 64; h4 += 4) {
            float4 wv4 = *(float4*)&lds[S_WV + h4];
            float4 bv4 = *(float4*)&lds[S_BV + h4];
            float wv_[4] = {wv4.x, wv4.y, wv4.z, wv4.w};
            float bv_[4] = {bv4.x, bv4.y, bv4.z, bv4.w};
#pragma unroll
            for (int hh = 0; hh < 4; ++hh) {
                float4 w = *(float4*)&lds[L_X + (h4 + hh) * 64 + ec * 4];
                float w_[4] = {w.x, w.y, w.z, w.w};
                float hv0 = fmaxf(fmaf(mc0, wv_[hh], bv_[hh]), 0.0f);
                float hv1 = fmaxf(fmaf(mc1, wv_[hh], bv_[hh]), 0.0f);
#pragma unroll
                for (int i = 0; i < 4; ++i) {
                    a0[i] = fmaf(hv0, w_[i], a0[i]);
                    a1[i] = fmaf(hv1, w_[i], a1[i]);
                }
            }
        }
        const int csbase = (sv > 0.5f) ? S_C1 : S_C0;
        float4 cs = *(float4*)&lds[csbase + ec * 4];
        float cs_[4] = {cs.x, cs.y, cs.z, cs.w};
        float4 dpv;
        dpv.x = fmaxf(a0[0] + cs_[0], 0.f) + fmaxf(a1[0] + cs_[0], 0.f);
        dpv.y = fmaxf(a0[1] + cs_[1], 0.f) + fmaxf(a1[1] + cs_[1], 0.f);
        dpv.z = fmaxf(a0[2] + cs_[2], 0.f) + fmaxf(a1[2] + cs_[2], 0.f);
        dpv.w = fmaxf(a0[3] + cs_[3], 0.f) + fmaxf(a1[3] + cs_[3], 0.f);
        *(float4*)&lds[L_DP + (mp * 8 + b) * 64 + ec * 4] = dpv;
    }
    __syncthreads();

    // ---- phase 2: U[p][j][b], V[p][j][b] ----
    {
        const int half = (t >> 5) & 1;       // 0 -> U, 1 -> V
        const int jj4  = (t & 31) * 4;
        const int wbase = L_W2 + (half ? 64 * 128 : 0);
        float acc[4][4] = {};
        for (int e = 0; e < 64; e += 2) {
            float4 w0 = *(float4*)&lds[wbase + e * 128 + jj4];
            float4 w1 = *(float4*)&lds[wbase + (e + 1) * 128 + jj4];
            float w0_[4] = {w0.x, w0.y, w0.z, w0.w};
            float w1_[4] = {w1.x, w1.y, w1.z, w1.w};
#pragma unroll
            for (int p = 0; p < 4; ++p) {
                float2 d2 = *(float2*)&lds[L_DP + (p * 8 + b) * 64 + e];
#pragma unroll
                for (int i = 0; i < 4; ++i) {
                    acc[p][i] = fmaf(d2.x, w0_[i], acc[p][i]);
                    acc[p][i] = fmaf(d2.y, w1_[i], acc[p][i]);
                }
            }
        }
        const int uvbase = L_UV + half * L_VOFF + b;
#pragma unroll
        for (int p = 0; p < 4; ++p)
#pragma unroll
            for (int i = 0; i < 4; ++i)
                lds[uvbase + p * 1160 + (jj4 + i) * 9] = acc[p][i];
    }
    __syncthreads();

    // ---- restage W2 with Wd2 (Wd1 dead) ----
    for (int i = t * 4; i < 16384; i += NT * 4)
        *(float4*)&lds[L_W2 + i] = *(const float4*)&Wd2_g[i];

    // ---- phase 3: two pair-groups of 8 (q in {0,1} then {2,3}) ----
    const float bcv = bc_g[0];
    const int row = t & 63;       // Hd1 row = pairLocal*8 + b
    const int jb  = t >> 6;       // j-block for staging
    const int mg  = t >> 5;       // GEMM m-group (4 rows)
    const int ng  = t & 31;       // GEMM n-group (4 cols)
    const int plr = row >> 3, bb = row & 7;
    const int ubase0 = L_UV + (plr >> 1) * 1160 + bb;

    for (int g = 0; g < 2; ++g) {
        {   // stage Hd1_T[j][row] = relu(U[p]+V[q]+bd1)
            const int q = 2 * g + (plr & 1);
            const int vbase = L_UV + L_VOFF + q * 1160 + bb;
#pragma unroll
            for (int jj = 0; jj < 16; ++jj) {
                const int j = jb * 16 + jj;
                float u = lds[ubase0 + j * 9];
                float v = lds[vbase + j * 9];
                lds[L_X + j * 68 + row] = fmaxf(u + v + lds[S_BD1 + j], 0.0f);
            }
        }
        __syncthreads();   // also covers Wd2 restage on g==0

        float acc[4][4] = {};
#pragma unroll 4
        for (int k = 0; k < 128; ++k) {
            float4 a4 = *(float4*)&lds[L_X + k * 68 + mg * 4];
            float4 w4 = *(float4*)&lds[L_W2 + k * 128 + ng * 4];
            float a_[4] = {a4.x, a4.y, a4.z, a4.w};
            float w_[4] = {w4.x, w4.y, w4.z, w4.w};
#pragma unroll
            for (int i = 0; i < 4; ++i)
#pragma unroll
                for (int jj = 0; jj < 4; ++jj)
                    acc[i][jj] = fmaf(a_[i], w_[jj], acc[i][jj]);
        }

        {   // epilogue: relu(+bd2), dot with wc_eff, reduce over ng, relu(+bc), store
            const int p = mg >> 2;
            const int q = 2 * g + ((mg >> 1) & 1);
            const int pairg = p * 4 + q;
            float4 b2 = *(float4*)&lds[S_BD2 + ng * 4];
            float4 wc = *(float4*)&lds[S_WC + pairg * 128 + ng * 4];
            float b2_[4] = {b2.x, b2.y, b2.z, b2.w};
            float wc_[4] = {wc.x, wc.y, wc.z, wc.w};
            float dot[4];
#pragma unroll
            for (int i = 0; i < 4; ++i) {
                dot[i] = fmaxf(acc[i][0] + b2_[0], 0.f) * wc_[0]
                       + fmaxf(acc[i][1] + b2_[1], 0.f) * wc_[1]
                       + fmaxf(acc[i][2] + b2_[2], 0.f) * wc_[2]
                       + fmaxf(acc[i][3] + b2_[3], 0.f) * wc_[3];
            }
#pragma unroll
            for (int off = 16; off > 0; off >>= 1) {
                dot[0] += __shfl_down(dot[0], off, 32);
                dot[1] += __shfl_down(dot[1], off, 32);
                dot[2] += __shfl_down(dot[2], off, 32);
                dot[3] += __shfl_down(dot[3], off, 32);
            }
            if (ng == 0) {
                float o = fmaxf(dot[0] + bcv, 0.f) + fmaxf(dot[1] + bcv, 0.f)
                        + fmaxf(dot[2] + bcv, 0.f) + fmaxf(dot[3] + bcv, 0.f);
                out[p * 32768 + q * 8192 + blockIdx.x * 2 + (mg & 1)] = o;
            }
        }
        __syncthreads();   // before next g overwrites Hd1_T
    }
}

extern "C" void kernel_launch(void* const* d_in, const int* in_sizes, int n_in,
                              void* d_out, int out_size, void* d_ws, size_t ws_size,
                              hipStream_t stream) {
    (void)in_sizes; (void)n_in; (void)out_size; (void)ws_size;
    const float* mc  = (const float*)d_in[0];
    const float* oh  = (const float*)d_in[1];
    const float* Wv  = (const float*)d_in[2];
    const float* bv  = (const float*)d_in[3];
    const float* Ws  = (const float*)d_in[4];
    const float* bs  = (const float*)d_in[5];
    const float* Wm  = (const float*)d_in[6];
    const float* bm  = (const float*)d_in[7];
    const float* rel = (const float*)d_in[8];
    const float* Wd1 = (const float*)d_in[9];
    const float* bd1 = (const float*)d_in[10];
    const float* Wd2 = (const float*)d_in[11];
    const float* bd2 = (const float*)d_in[12];
    const float* Wr1 = (const float*)d_in[13];
    const float* br1 = (const float*)d_in[14];
    const float* Wr2 = (const float*)d_in[15];
    const float* br2 = (const float*)d_in[16];
    const float* Wc  = (const float*)d_in[17];
    const float* bc  = (const float*)d_in[18];
    float* wsf = (float*)d_ws;
    float* out = (float*)d_out;

    hipLaunchKernelGGL(frap_setup, dim3(17), dim3(128), 0, stream,
                       Ws, bs, Wm, bm, rel, Wr1, br1, Wr2, br2, Wc, wsf);
    hipLaunchKernelGGL(frap_main, dim3(NBLK), dim3(NT), LDS_FLOATS * 4, stream,
                       mc, oh, Wv, bv, Wm, Wd1, bd1, Wd2, bd2, bc, wsf, out);
}

// Round 2
// 380.154 us; speedup vs baseline: 2.3716x; 2.3716x over previous
//
#include <hip/hip_runtime.h>

#define NT   512
#define NBLK 4096   // B/8

typedef _Float16 half8 __attribute__((ext_vector_type(8)));
typedef float    f32x4 __attribute__((ext_vector_type(4)));

// ---- LDS float offsets ----
#define L_WD1  0                 // 16384 f fp32 Wd1 (phases 1-2); A_f16 (8192 f) overlays after
#define L_B    16384             // 8192 f = Wd2T f16 swizzled [col][128k]
#define L_UV   24576             // U:[4][128][9] stride 1160, V at +4640; Wm_top overlays in phase 1
#define L_WM   24576
#define L_VOFF 4640
#define L_DP   33856             // dp [4][8][64] = 2048 f
#define L_S    35904
#define S_WV   (L_S + 0)         // 64
#define S_BV   (L_S + 64)        // 64
#define S_BD1  (L_S + 128)      // 128
#define S_BD2  (L_S + 256)      // 128
#define S_C0   (L_S + 384)      // 64
#define S_C1   (L_S + 448)      // 64
#define S_WC   (L_S + 512)      // 2048
#define S_SP   (L_S + 2560)     // S_part[2][128]
#define LDS_FLOATS (L_S + 2816) // 38720 f = 154880 B

// ws float layout: [0,2048) wc_eff ; [2048,2176) c0/c1 ; [2304,6400) Wd2T f16 swz (16KB)
#define WS_B_F 2304

__global__ void frap_setup(const float* __restrict__ Ws0, const float* __restrict__ bs,
                           const float* __restrict__ Wm,  const float* __restrict__ bm,
                           const float* __restrict__ rel, const float* __restrict__ Wr1,
                           const float* __restrict__ br1, const float* __restrict__ Wr2,
                           const float* __restrict__ br2, const float* __restrict__ Wc,
                           const float* __restrict__ Wd2, float* __restrict__ wsf)
{
    __shared__ float hr1[128];
    const int t = threadIdx.x;  // 128 threads
    if (blockIdx.x == 16) {
        const int s = t >> 6, e = t & 63;
        float acc = bm[e];
        for (int h = 0; h < 64; ++h) {
            float hs = fmaxf((s ? Ws0[h] : 0.0f) + bs[h], 0.0f);
            acc = fmaf(hs, Wm[(64 + h) * 64 + e], acc);
        }
        wsf[2048 + s * 64 + e] = acc;
    } else if (blockIdx.x == 17) {
        // Wd2T -> f16, transposed, XOR-swizzled: 16B chunk c16 of row `col`
        // stored at byte  col*256 + ((c16 ^ (col&7))<<4)
        const int col = t;
        for (int c16 = 0; c16 < 16; ++c16) {
            half8 v;
#pragma unroll
            for (int kk = 0; kk < 8; ++kk)
                v[kk] = (_Float16)Wd2[(c16 * 8 + kk) * 128 + col];
            *(half8*)((char*)wsf + WS_B_F * 4 + col * 256 + ((c16 ^ (col & 7)) << 4)) = v;
        }
    } else {
        const int pair = blockIdx.x;  // p*4+q
        float a = br1[t];
        for (int r = 0; r < 32; ++r) a = fmaf(rel[pair * 32 + r], Wr1[r * 128 + t], a);
        hr1[t] = fmaxf(a, 0.0f);
        __syncthreads();
        float a2 = br2[t];
        for (int j = 0; j < 128; ++j) a2 = fmaf(hr1[j], Wr2[j * 128 + t], a2);
        wsf[pair * 128 + t] = fmaxf(a2, 0.0f) * Wc[t];  // wc_eff
    }
}

__global__ __launch_bounds__(NT, 2)
void frap_main(const float* __restrict__ mc_g, const float* __restrict__ oh_g,
               const float* __restrict__ Wv_g, const float* __restrict__ bv_g,
               const float* __restrict__ Wm_g,
               const float* __restrict__ Wd1_g, const float* __restrict__ bd1_g,
               const float* __restrict__ bd2_g, const float* __restrict__ bc_g,
               const float* __restrict__ wsf, float* __restrict__ out)
{
    extern __shared__ float lds[];
    const int t = threadIdx.x;

    // ---- stage constants + Wm_top + Wd1 (fp32) + B (f16 swz, pre-swizzled in ws) ----
    if (t < 64) {
        lds[S_WV + t] = Wv_g[t];
        lds[S_BV + t] = bv_g[t];
        lds[S_C0 + t] = wsf[2048 + t];
        lds[S_C1 + t] = wsf[2112 + t];
    } else if (t < 192) {
        lds[S_BD1 + (t - 64)] = bd1_g[t - 64];
    } else if (t < 320) {
        lds[S_BD2 + (t - 192)] = bd2_g[t - 192];
    }
    for (int i = t; i < 2048; i += NT) lds[S_WC + i] = wsf[i];
    for (int i = t; i < 4096; i += NT) lds[L_WM + i] = Wm_g[i];
    for (int i = t * 4; i < 16384; i += NT * 4)
        *(float4*)&lds[L_WD1 + i] = *(const float4*)&Wd1_g[i];
    for (int i = t * 4; i < 8192; i += NT * 4)
        *(float4*)&lds[L_B + i] = *(const float4*)&wsf[WS_B_F + i];
    __syncthreads();

    const int b  = t >> 6;         // 0..7
    const int mp = (t >> 4) & 3;   // movement pair = phase index p
    const int ec = t & 15;         // e-chunk of 4
    const int bg = blockIdx.x * 8 + b;

    // ---- phase 1: d_p[p][e] ----
    {
        const float mc0 = mc_g[bg * 8 + 2 * mp];
        const float mc1 = mc_g[bg * 8 + 2 * mp + 1];
        const float sv  = oh_g[bg * 4 + mp];
        float a0[4] = {0.f, 0.f, 0.f, 0.f};
        float a1[4] = {0.f, 0.f, 0.f, 0.f};
        for (int h4 = 0; h4 < 64; h4 += 4) {
            float4 wv4 = *(float4*)&lds[S_WV + h4];
            float4 bv4 = *(float4*)&lds[S_BV + h4];
            float wv_[4] = {wv4.x, wv4.y, wv4.z, wv4.w};
            float bv_[4] = {bv4.x, bv4.y, bv4.z, bv4.w};
#pragma unroll
            for (int hh = 0; hh < 4; ++hh) {
                float4 w = *(float4*)&lds[L_WM + (h4 + hh) * 64 + ec * 4];
                float w_[4] = {w.x, w.y, w.z, w.w};
                float hv0 = fmaxf(fmaf(mc0, wv_[hh], bv_[hh]), 0.0f);
                float hv1 = fmaxf(fmaf(mc1, wv_[hh], bv_[hh]), 0.0f);
#pragma unroll
                for (int i = 0; i < 4; ++i) {
                    a0[i] = fmaf(hv0, w_[i], a0[i]);
                    a1[i] = fmaf(hv1, w_[i], a1[i]);
                }
            }
        }
        const int csbase = (sv > 0.5f) ? S_C1 : S_C0;
        float4 cs = *(float4*)&lds[csbase + ec * 4];
        float cs_[4] = {cs.x, cs.y, cs.z, cs.w};
        float4 dpv;
        dpv.x = fmaxf(a0[0] + cs_[0], 0.f) + fmaxf(a1[0] + cs_[0], 0.f);
        dpv.y = fmaxf(a0[1] + cs_[1], 0.f) + fmaxf(a1[1] + cs_[1], 0.f);
        dpv.z = fmaxf(a0[2] + cs_[2], 0.f) + fmaxf(a1[2] + cs_[2], 0.f);
        dpv.w = fmaxf(a0[3] + cs_[3], 0.f) + fmaxf(a1[3] + cs_[3], 0.f);
        *(float4*)&lds[L_DP + (mp * 8 + b) * 64 + ec * 4] = dpv;
    }
    __syncthreads();

    // ---- phase 2: U[p][j][b], V[q][j][b] ----
    {
        const int half = (t >> 5) & 1;       // 0 -> U, 1 -> V
        const int jj4  = (t & 31) * 4;
        const int wbase = L_WD1 + (half ? 64 * 128 : 0);
        float acc[4][4] = {};
        for (int e = 0; e < 64; e += 2) {
            float4 w0 = *(float4*)&lds[wbase + e * 128 + jj4];
            float4 w1 = *(float4*)&lds[wbase + (e + 1) * 128 + jj4];
            float w0_[4] = {w0.x, w0.y, w0.z, w0.w};
            float w1_[4] = {w1.x, w1.y, w1.z, w1.w};
#pragma unroll
            for (int p = 0; p < 4; ++p) {
                float2 d2 = *(float2*)&lds[L_DP + (p * 8 + b) * 64 + e];
#pragma unroll
                for (int i = 0; i < 4; ++i) {
                    acc[p][i] = fmaf(d2.x, w0_[i], acc[p][i]);
                    acc[p][i] = fmaf(d2.y, w1_[i], acc[p][i]);
                }
            }
        }
        const int uvbase = L_UV + half * L_VOFF + b;
#pragma unroll
        for (int p = 0; p < 4; ++p)
#pragma unroll
            for (int i = 0; i < 4; ++i)
                lds[uvbase + p * 1160 + (jj4 + i) * 9] = acc[p][i];
    }
    __syncthreads();

    // ---- phase 2.5: A[r][j] = relu(U+V+bd1) -> f16, XOR-swizzled, overlays Wd1 ----
    {
        const int r  = t & 127;
        const int cb = (t >> 7) << 2;
        const int p  = r >> 5, q = (r >> 3) & 3, bb2 = r & 7;
        const int ub = L_UV + p * 1160 + bb2;
        const int vb = L_UV + L_VOFF + q * 1160 + bb2;
        const int sw = r & 7;
#pragma unroll
        for (int cc = 0; cc < 4; ++cc) {
            const int c16 = cb + cc;
            half8 v;
#pragma unroll
            for (int jj = 0; jj < 8; ++jj) {
                const int j = c16 * 8 + jj;
                float a = lds[ub + j * 9] + lds[vb + j * 9] + lds[S_BD1 + j];
                v[jj] = (_Float16)fmaxf(a, 0.0f);
            }
            *(half8*)((char*)lds + r * 256 + ((c16 ^ sw) << 4)) = v;
        }
    }
    __syncthreads();

    // ---- phase 3: MFMA 128x128x128, f16 inputs, fp32 accumulate ----
    const int w    = t >> 6;
    const int lane = t & 63;
    const int lr   = lane & 15, lq = lane >> 4;
    const int rtb  = (w & 3) * 2;   // 2 row-tiles: rows 32*(w&3)..+31
    const int ctb  = (w >> 2) * 4;  // 4 col-tiles: cols 64*(w>>2)..+63

    f32x4 acc[2][4];
#pragma unroll
    for (int i = 0; i < 2; ++i)
#pragma unroll
        for (int j = 0; j < 4; ++j) acc[i][j] = (f32x4){0.f, 0.f, 0.f, 0.f};

#pragma unroll
    for (int ks = 0; ks < 4; ++ks) {
        const int c16 = ks * 4 + lq;
        half8 af[2], bf[4];
#pragma unroll
        for (int i = 0; i < 2; ++i) {
            const int r = (rtb + i) * 16 + lr;
            af[i] = *(half8*)((char*)lds + r * 256 + ((c16 ^ (r & 7)) << 4));
        }
#pragma unroll
        for (int j = 0; j < 4; ++j) {
            const int col = (ctb + j) * 16 + lr;
            bf[j] = *(half8*)((char*)lds + L_B * 4 + col * 256 + ((c16 ^ (col & 7)) << 4));
        }
#pragma unroll
        for (int i = 0; i < 2; ++i)
#pragma unroll
            for (int j = 0; j < 4; ++j)
                acc[i][j] = __builtin_amdgcn_mfma_f32_16x16x32_f16(af[i], bf[j], acc[i][j], 0, 0, 0);
    }

    // ---- epilogue: relu(+bd2) * wc_eff, reduce cols, cross-wave via LDS ----
    {
        float part[2][4];
#pragma unroll
        for (int rt = 0; rt < 2; ++rt)
#pragma unroll
            for (int ii = 0; ii < 4; ++ii) {
                const int row = (rtb + rt) * 16 + 4 * lq + ii;
                const int wcb = S_WC + (row >> 3) * 128;
                float pr = 0.f;
#pragma unroll
                for (int ct = 0; ct < 4; ++ct) {
                    const int col = (ctb + ct) * 16 + lr;
                    pr = fmaf(fmaxf(acc[rt][ct][ii] + lds[S_BD2 + col], 0.f), lds[wcb + col], pr);
                }
                part[rt][ii] = pr;
            }
#pragma unroll
        for (int off = 1; off < 16; off <<= 1) {
#pragma unroll
            for (int rt = 0; rt < 2; ++rt)
#pragma unroll
                for (int ii = 0; ii < 4; ++ii)
                    part[rt][ii] += __shfl_xor(part[rt][ii], off, 64);
        }
        if (lr < 8) {
            const int rt = lr >> 2, ii = lr & 3;
            const int row = (rtb + rt) * 16 + 4 * lq + ii;
            lds[S_SP + (w >> 2) * 128 + row] = part[rt][ii];
        }
    }
    __syncthreads();

    if (t < 32) {
        const float bcv = bc_g[0];
        float o = 0.f;
#pragma unroll
        for (int d = 0; d < 4; ++d) {
            const int r = t * 4 + d;
            o += fmaxf(lds[S_SP + r] + lds[S_SP + 128 + r] + bcv, 0.f);
        }
        const int p_ = t >> 3, q_ = (t >> 1) & 3;
        out[p_ * 32768 + q_ * 8192 + blockIdx.x * 2 + (t & 1)] = o;
    }
}

extern "C" void kernel_launch(void* const* d_in, const int* in_sizes, int n_in,
                              void* d_out, int out_size, void* d_ws, size_t ws_size,
                              hipStream_t stream) {
    (void)in_sizes; (void)n_in; (void)out_size; (void)ws_size;
    const float* mc  = (const float*)d_in[0];
    const float* oh  = (const float*)d_in[1];
    const float* Wv  = (const float*)d_in[2];
    const float* bv  = (const float*)d_in[3];
    const float* Ws  = (const float*)d_in[4];
    const float* bs  = (const float*)d_in[5];
    const float* Wm  = (const float*)d_in[6];
    const float* bm  = (const float*)d_in[7];
    const float* rel = (const float*)d_in[8];
    const float* Wd1 = (const float*)d_in[9];
    const float* bd1 = (const float*)d_in[10];
    const float* Wd2 = (const float*)d_in[11];
    const float* bd2 = (const float*)d_in[12];
    const float* Wr1 = (const float*)d_in[13];
    const float* br1 = (const float*)d_in[14];
    const float* Wr2 = (const float*)d_in[15];
    const float* br2 = (const float*)d_in[16];
    const float* Wc  = (const float*)d_in[17];
    const float* bc  = (const float*)d_in[18];
    float* wsf = (float*)d_ws;
    float* out = (float*)d_out;

    hipLaunchKernelGGL(frap_setup, dim3(18), dim3(128), 0, stream,
                       Ws, bs, Wm, bm, rel, Wr1, br1, Wr2, br2, Wc, Wd2, wsf);
    hipLaunchKernelGGL(frap_main, dim3(NBLK), dim3(NT), LDS_FLOATS * 4, stream,
                       mc, oh, Wv, bv, Wm, Wd1, bd1, bd2, bc, wsf, out);
}

// Round 3
// 170.140 us; speedup vs baseline: 5.2989x; 2.2344x over previous
//
#include <hip/hip_runtime.h>

#define NT   512
#define NBLK 4096   // B/8

typedef _Float16 half8 __attribute__((ext_vector_type(8)));
typedef _Float16 half4 __attribute__((ext_vector_type(4)));
typedef float    f32x4 __attribute__((ext_vector_type(4)));

// ---- LDS float offsets ----
#define L_W1   0        // 8192 f: Wd1T f16 swz (32KB); A2 f16 swz overlays after GEMM-1
#define L_W2   8192     // 8192 f: Wd2T f16 swz (32KB)
#define L_DPH  16384    // 1024 f: dpH f16 swz [32 rows][128B]
#define L_S    17408
#define S_WV   (L_S + 0)     // 64
#define S_BV   (L_S + 64)    // 64
#define S_BD1  (L_S + 128)   // 128
#define S_BD2  (L_S + 256)   // 128
#define S_SP   (L_S + 384)   // 256: S_part[2][128]
#define LDS_FLOATS (L_S + 640)   // 18048 f = 72192 B -> 2 blocks/CU

// ---- ws float offsets ----
// [0,2048) wc_eff fp32 ; [2048,2176) c0/c1 ; Wd2T f16 swz ; Wd1T f16 swz
#define WS_CS  2048
#define WS_W2  2304
#define WS_W1  10496

__global__ void frap_setup(const float* __restrict__ Ws0, const float* __restrict__ bs,
                           const float* __restrict__ Wm,  const float* __restrict__ bm,
                           const float* __restrict__ rel, const float* __restrict__ Wr1,
                           const float* __restrict__ br1, const float* __restrict__ Wr2,
                           const float* __restrict__ br2, const float* __restrict__ Wc,
                           const float* __restrict__ Wd1, const float* __restrict__ Wd2,
                           float* __restrict__ wsf)
{
    __shared__ float hr1[128];
    const int t = threadIdx.x;  // 128 threads
    if (blockIdx.x == 16) {
        const int s = t >> 6, e = t & 63;
        float acc = bm[e];
        for (int h = 0; h < 64; ++h) {
            float hs = fmaxf((s ? Ws0[h] : 0.0f) + bs[h], 0.0f);
            acc = fmaf(hs, Wm[(64 + h) * 64 + e], acc);
        }
        wsf[WS_CS + s * 64 + e] = acc;
    } else if (blockIdx.x >= 17) {
        // W[128][128] -> WT f16, transposed, XOR-swizzled:
        // 16B chunk c16 of row `col` at byte col*256 + ((c16 ^ (col&7))<<4)
        const float* Wsrc = (blockIdx.x == 17) ? Wd2 : Wd1;
        const int ofs = (blockIdx.x == 17) ? WS_W2 : WS_W1;
        const int col = t;
        for (int c16 = 0; c16 < 16; ++c16) {
            half8 v;
#pragma unroll
            for (int kk = 0; kk < 8; ++kk)
                v[kk] = (_Float16)Wsrc[(c16 * 8 + kk) * 128 + col];
            *(half8*)((char*)wsf + ofs * 4 + col * 256 + ((c16 ^ (col & 7)) << 4)) = v;
        }
    } else {
        const int pair = blockIdx.x;  // p*4+q
        float a = br1[t];
        for (int r = 0; r < 32; ++r) a = fmaf(rel[pair * 32 + r], Wr1[r * 128 + t], a);
        hr1[t] = fmaxf(a, 0.0f);
        __syncthreads();
        float a2 = br2[t];
        for (int j = 0; j < 128; ++j) a2 = fmaf(hr1[j], Wr2[j * 128 + t], a2);
        wsf[pair * 128 + t] = fmaxf(a2, 0.0f) * Wc[t];  // wc_eff
    }
}

__global__ __launch_bounds__(NT, 4)
void frap_main(const float* __restrict__ mc_g, const float* __restrict__ oh_g,
               const float* __restrict__ Wv_g, const float* __restrict__ bv_g,
               const float* __restrict__ Wm_g,
               const float* __restrict__ bd1_g, const float* __restrict__ bd2_g,
               const float* __restrict__ bc_g,
               const float* __restrict__ wsf, float* __restrict__ out)
{
    extern __shared__ float lds[];
    const int t = threadIdx.x;

    // ---- stage consts + Wd1T + Wd2T (pre-swizzled f16 from ws) ----
    if (t < 64) {
        lds[S_WV + t] = Wv_g[t];
        lds[S_BV + t] = bv_g[t];
    } else if (t < 192) {
        lds[S_BD1 + (t - 64)] = bd1_g[t - 64];
    } else if (t < 320) {
        lds[S_BD2 + (t - 192)] = bd2_g[t - 192];
    }
    for (int i = t * 4; i < 8192; i += NT * 4) {
        *(float4*)&lds[L_W1 + i] = *(const float4*)&wsf[WS_W1 + i];
        *(float4*)&lds[L_W2 + i] = *(const float4*)&wsf[WS_W2 + i];
    }
    __syncthreads();

    const int b  = t >> 6;         // 0..7 (wave index)
    const int mp = (t >> 4) & 3;   // movement pair = phase p
    const int ec = t & 15;         // e-chunk of 4
    const int bg = blockIdx.x * 8 + b;

    // ---- phase 1: d_p -> dpH f16 swizzled [32][64] ----
    {
        const float mc0 = mc_g[bg * 8 + 2 * mp];
        const float mc1 = mc_g[bg * 8 + 2 * mp + 1];
        const float sv  = oh_g[bg * 4 + mp];
        float a0[4] = {0.f, 0.f, 0.f, 0.f};
        float a1[4] = {0.f, 0.f, 0.f, 0.f};
        for (int h4 = 0; h4 < 64; h4 += 4) {
            float4 wv4 = *(float4*)&lds[S_WV + h4];
            float4 bv4 = *(float4*)&lds[S_BV + h4];
            float wv_[4] = {wv4.x, wv4.y, wv4.z, wv4.w};
            float bv_[4] = {bv4.x, bv4.y, bv4.z, bv4.w};
#pragma unroll
            for (int hh = 0; hh < 4; ++hh) {
                float4 w = *(const float4*)&Wm_g[(h4 + hh) * 64 + ec * 4];
                float w_[4] = {w.x, w.y, w.z, w.w};
                float hv0 = fmaxf(fmaf(mc0, wv_[hh], bv_[hh]), 0.0f);
                float hv1 = fmaxf(fmaf(mc1, wv_[hh], bv_[hh]), 0.0f);
#pragma unroll
                for (int i = 0; i < 4; ++i) {
                    a0[i] = fmaf(hv0, w_[i], a0[i]);
                    a1[i] = fmaf(hv1, w_[i], a1[i]);
                }
            }
        }
        float4 cs = *(const float4*)&wsf[WS_CS + ((sv > 0.5f) ? 64 : 0) + ec * 4];
        float cs_[4] = {cs.x, cs.y, cs.z, cs.w};
        half4 hv;
#pragma unroll
        for (int i = 0; i < 4; ++i) {
            float ai = (i == 0) ? a0[0] : (i == 1) ? a0[1] : (i == 2) ? a0[2] : a0[3];
            float bi = (i == 0) ? a1[0] : (i == 1) ? a1[1] : (i == 2) ? a1[2] : a1[3];
            hv[i] = (_Float16)(fmaxf(ai + cs_[i], 0.f) + fmaxf(bi + cs_[i], 0.f));
        }
        const int row32 = mp * 8 + b;
        *(half4*)((char*)lds + L_DPH * 4 + row32 * 128
                  + (((ec >> 1) ^ (row32 & 7)) << 4) + (ec & 1) * 8) = hv;
    }
    __syncthreads();

    const int w    = t >> 6;
    const int lane = t & 63;
    const int lr   = lane & 15, lq = lane >> 4;
    const int rtb  = (w & 3) * 2;   // 2 row-tiles
    const int ctb  = (w >> 2) * 4;  // 4 col-tiles

    // ---- GEMM-1: Hd1 = relu(A2 @ Wd1 + bd1), A2 rows (p,q,b) read from dpH ----
    {
        f32x4 acc1[2][4];
#pragma unroll
        for (int i = 0; i < 2; ++i)
#pragma unroll
            for (int j = 0; j < 4; ++j) acc1[i][j] = (f32x4){0.f, 0.f, 0.f, 0.f};

#pragma unroll
        for (int ks = 0; ks < 4; ++ks) {
            const int c16 = ks * 4 + lq;
            const int c8  = (ks & 1) * 4 + lq;
            half8 af[2], bf[4];
#pragma unroll
            for (int i = 0; i < 2; ++i) {
                const int r  = (rtb + i) * 16 + lr;
                const int pq = (ks < 2) ? (r >> 5) : ((r >> 3) & 3);
                const int row32 = pq * 8 + (r & 7);
                af[i] = *(half8*)((char*)lds + L_DPH * 4 + row32 * 128 + ((c8 ^ (r & 7)) << 4));
            }
#pragma unroll
            for (int j = 0; j < 4; ++j) {
                const int col = (ctb + j) * 16 + lr;
                bf[j] = *(half8*)((char*)lds + L_W1 * 4 + col * 256 + ((c16 ^ (col & 7)) << 4));
            }
#pragma unroll
            for (int i = 0; i < 2; ++i)
#pragma unroll
                for (int j = 0; j < 4; ++j)
                    acc1[i][j] = __builtin_amdgcn_mfma_f32_16x16x32_f16(af[i], bf[j], acc1[i][j], 0, 0, 0);
        }
        __syncthreads();   // all Wd1T reads done before A2 overlays it

        // epilogue: +bd1, relu, cvt f16, store A2 swizzled over L_W1
#pragma unroll
        for (int rt = 0; rt < 2; ++rt)
#pragma unroll
            for (int reg = 0; reg < 4; ++reg) {
                const int row = (rtb + rt) * 16 + lq * 4 + reg;
                const int sw  = row & 7;
#pragma unroll
                for (int ct = 0; ct < 4; ++ct) {
                    const int col = (ctb + ct) * 16 + lr;
                    float hval = fmaxf(acc1[rt][ct][reg] + lds[S_BD1 + col], 0.f);
                    *(_Float16*)((char*)lds + L_W1 * 4 + row * 256
                                 + (((col >> 3) ^ sw) << 4) + (col & 7) * 2) = (_Float16)hval;
                }
            }
    }
    __syncthreads();

    // ---- GEMM-2: Hd2-side, A = A2 (L_W1), B = Wd2T (L_W2) ----
    f32x4 acc[2][4];
#pragma unroll
    for (int i = 0; i < 2; ++i)
#pragma unroll
        for (int j = 0; j < 4; ++j) acc[i][j] = (f32x4){0.f, 0.f, 0.f, 0.f};

#pragma unroll
    for (int ks = 0; ks < 4; ++ks) {
        const int c16 = ks * 4 + lq;
        half8 af[2], bf[4];
#pragma unroll
        for (int i = 0; i < 2; ++i) {
            const int r = (rtb + i) * 16 + lr;
            af[i] = *(half8*)((char*)lds + L_W1 * 4 + r * 256 + ((c16 ^ (r & 7)) << 4));
        }
#pragma unroll
        for (int j = 0; j < 4; ++j) {
            const int col = (ctb + j) * 16 + lr;
            bf[j] = *(half8*)((char*)lds + L_W2 * 4 + col * 256 + ((c16 ^ (col & 7)) << 4));
        }
#pragma unroll
        for (int i = 0; i < 2; ++i)
#pragma unroll
            for (int j = 0; j < 4; ++j)
                acc[i][j] = __builtin_amdgcn_mfma_f32_16x16x32_f16(af[i], bf[j], acc[i][j], 0, 0, 0);
    }

    // ---- epilogue: relu(+bd2) * wc_eff (global, L1-hot), reduce, store ----
    {
        float part[2][4];
#pragma unroll
        for (int rt = 0; rt < 2; ++rt)
#pragma unroll
            for (int ii = 0; ii < 4; ++ii) {
                const int row = (rtb + rt) * 16 + 4 * lq + ii;
                const float* wcr = &wsf[(row >> 3) * 128];
                float pr = 0.f;
#pragma unroll
                for (int ct = 0; ct < 4; ++ct) {
                    const int col = (ctb + ct) * 16 + lr;
                    pr = fmaf(fmaxf(acc[rt][ct][ii] + lds[S_BD2 + col], 0.f), wcr[col], pr);
                }
                part[rt][ii] = pr;
            }
#pragma unroll
        for (int off = 1; off < 16; off <<= 1) {
#pragma unroll
            for (int rt = 0; rt < 2; ++rt)
#pragma unroll
                for (int ii = 0; ii < 4; ++ii)
                    part[rt][ii] += __shfl_xor(part[rt][ii], off, 64);
        }
        if (lr < 8) {
            const int rt = lr >> 2, ii = lr & 3;
            const int row = (rtb + rt) * 16 + 4 * lq + ii;
            lds[S_SP + (w >> 2) * 128 + row] = part[rt][ii];
        }
    }
    __syncthreads();

    if (t < 32) {
        const float bcv = bc_g[0];
        float o = 0.f;
#pragma unroll
        for (int d = 0; d < 4; ++d) {
            const int r = t * 4 + d;
            o += fmaxf(lds[S_SP + r] + lds[S_SP + 128 + r] + bcv, 0.f);
        }
        const int p_ = t >> 3, q_ = (t >> 1) & 3;
        out[p_ * 32768 + q_ * 8192 + blockIdx.x * 2 + (t & 1)] = o;
    }
}

extern "C" void kernel_launch(void* const* d_in, const int* in_sizes, int n_in,
                              void* d_out, int out_size, void* d_ws, size_t ws_size,
                              hipStream_t stream) {
    (void)in_sizes; (void)n_in; (void)out_size; (void)ws_size;
    const float* mc  = (const float*)d_in[0];
    const float* oh  = (const float*)d_in[1];
    const float* Wv  = (const float*)d_in[2];
    const float* bv  = (const float*)d_in[3];
    const float* Ws  = (const float*)d_in[4];
    const float* bs  = (const float*)d_in[5];
    const float* Wm  = (const float*)d_in[6];
    const float* bm  = (const float*)d_in[7];
    const float* rel = (const float*)d_in[8];
    const float* Wd1 = (const float*)d_in[9];
    const float* bd1 = (const float*)d_in[10];
    const float* Wd2 = (const float*)d_in[11];
    const float* bd2 = (const float*)d_in[12];
    const float* Wr1 = (const float*)d_in[13];
    const float* br1 = (const float*)d_in[14];
    const float* Wr2 = (const float*)d_in[15];
    const float* br2 = (const float*)d_in[16];
    const float* Wc  = (const float*)d_in[17];
    const float* bc  = (const float*)d_in[18];
    float* wsf = (float*)d_ws;
    float* out = (float*)d_out;

    hipLaunchKernelGGL(frap_setup, dim3(19), dim3(128), 0, stream,
                       Ws, bs, Wm, bm, rel, Wr1, br1, Wr2, br2, Wc, Wd1, Wd2, wsf);
    hipLaunchKernelGGL(frap_main, dim3(NBLK), dim3(NT), LDS_FLOATS * 4, stream,
                       mc, oh, Wv, bv, Wm, bd1, bd2, bc, wsf, out);
}

// Round 4
// 135.655 us; speedup vs baseline: 6.6459x; 1.2542x over previous
//
#include <hip/hip_runtime.h>

#define NT   512
#define NBLK 4096   // B/8

typedef _Float16 half8 __attribute__((ext_vector_type(8)));
typedef float    f32x4 __attribute__((ext_vector_type(4)));

// ---- LDS float offsets ----
#define L_W1   0            // 8192 f: Wd1T f16 swz (32KB); A2 overlays after GEMM-1
#define L_W2   8192         // 8192 f: early Ah(8KB)+WmT(8KB); late Wd2T f16 swz (32KB)
#define L_AH   L_W2         // 2048 f
#define L_WM   (L_W2 + 2048) // 2048 f
#define L_DPH  16384        // 1024 f: dpH f16 swz [32 rows][128B]
#define L_S    17408
#define S_BD1  (L_S + 0)    // 128
#define S_BD2  (L_S + 128)  // 128
#define S_C0   (L_S + 256)  // 64
#define S_C1   (L_S + 320)  // 64
#define S_SP   (L_S + 384)  // 256: S_part[2][128]
#define LDS_FLOATS (L_S + 640)   // 18048 f = 72192 B -> 2 blocks/CU

// ---- ws float offsets ----
#define WS_CS  2048    // c0/c1 (128 f)
#define WS_W2  2304    // Wd2T f16 swz (8192 f)
#define WS_W1  10496   // Wd1T f16 swz (8192 f)
#define WS_WM  18688   // WmT  f16 swz (2048 f)

#define GLOAD(gbyte, lbyte) \
    __builtin_amdgcn_global_load_lds( \
        (const __attribute__((address_space(1))) unsigned int*)(const void*)((const char*)wsf + (size_t)(gbyte)), \
        (__attribute__((address_space(3))) unsigned int*)(void*)((char*)lds + (size_t)(lbyte)), 16, 0, 0)

__global__ void frap_setup(const float* __restrict__ Ws0, const float* __restrict__ bs,
                           const float* __restrict__ Wm,  const float* __restrict__ bm,
                           const float* __restrict__ rel, const float* __restrict__ Wr1,
                           const float* __restrict__ br1, const float* __restrict__ Wr2,
                           const float* __restrict__ br2, const float* __restrict__ Wc,
                           const float* __restrict__ Wd1, const float* __restrict__ Wd2,
                           float* __restrict__ wsf)
{
    __shared__ float hr1[128];
    const int t = threadIdx.x;  // 128 threads
    if (blockIdx.x == 16) {
        const int s = t >> 6, e = t & 63;
        float acc = bm[e];
        for (int h = 0; h < 64; ++h) {
            float hs = fmaxf((s ? Ws0[h] : 0.0f) + bs[h], 0.0f);
            acc = fmaf(hs, Wm[(64 + h) * 64 + e], acc);
        }
        wsf[WS_CS + s * 64 + e] = acc;
    } else if (blockIdx.x == 17 || blockIdx.x == 18) {
        // W[128][128] -> WT f16, transposed, XOR-swizzled:
        // 16B chunk c16 of row `col` at byte col*256 + ((c16 ^ (col&7))<<4)
        const float* Wsrc = (blockIdx.x == 17) ? Wd2 : Wd1;
        const int ofs = (blockIdx.x == 17) ? WS_W2 : WS_W1;
        const int col = t;
        for (int c16 = 0; c16 < 16; ++c16) {
            half8 v;
#pragma unroll
            for (int kk = 0; kk < 8; ++kk)
                v[kk] = (_Float16)Wsrc[(c16 * 8 + kk) * 128 + col];
            *(half8*)((char*)wsf + ofs * 4 + col * 256 + ((c16 ^ (col & 7)) << 4)) = v;
        }
    } else if (blockIdx.x == 19) {
        // Wm_top[64h][64e] -> WmT f16: col=e (128B rows of 64 f16), chunk c8 swz
        if (t < 64) {
            const int e = t;
            for (int c8 = 0; c8 < 8; ++c8) {
                half8 v;
#pragma unroll
                for (int kk = 0; kk < 8; ++kk)
                    v[kk] = (_Float16)Wm[(c8 * 8 + kk) * 64 + e];
                *(half8*)((char*)wsf + WS_WM * 4 + e * 128 + ((c8 ^ (e & 7)) << 4)) = v;
            }
        }
    } else {
        const int pair = blockIdx.x;  // p*4+q
        float a = br1[t];
        for (int r = 0; r < 32; ++r) a = fmaf(rel[pair * 32 + r], Wr1[r * 128 + t], a);
        hr1[t] = fmaxf(a, 0.0f);
        __syncthreads();
        float a2 = br2[t];
        for (int j = 0; j < 128; ++j) a2 = fmaf(hr1[j], Wr2[j * 128 + t], a2);
        wsf[pair * 128 + t] = fmaxf(a2, 0.0f) * Wc[t];  // wc_eff
    }
}

__global__ __launch_bounds__(NT, 4)
void frap_main(const float* __restrict__ mc_g, const float* __restrict__ oh_g,
               const float* __restrict__ Wv_g, const float* __restrict__ bv_g,
               const float* __restrict__ bd1_g, const float* __restrict__ bd2_g,
               const float* __restrict__ bc_g,
               const float* __restrict__ wsf, float* __restrict__ out)
{
    extern __shared__ float lds[];
    const int t = threadIdx.x;
    const int wv = t >> 6, ln = t & 63;
    const int bid = blockIdx.x;

    // ---- async stage: WmT (1 rnd, 8KB) then W1 (4 rnds, 32KB) ----
    GLOAD(WS_WM * 4 + wv * 1024 + ln * 16, L_WM * 4 + wv * 1024);
#pragma unroll
    for (int rr = 0; rr < 4; ++rr)
        GLOAD(WS_W1 * 4 + rr * 8192 + wv * 1024 + ln * 16, L_W1 * 4 + rr * 8192 + wv * 1024);

    // ---- consts ----
    if (t < 128) lds[S_BD1 + t] = bd1_g[t];
    else if (t < 256) lds[S_BD2 + (t - 128)] = bd2_g[t - 128];
    else if (t < 384) lds[S_C0 + (t - 256)] = wsf[WS_CS + (t - 256)];

    // ---- Ah[r=b*8+mv][64h] = relu(mc*Wv+bv) f16 swz ----
    {
        const int r = t >> 3, h8 = (t & 7) * 8;
        const float mcv = mc_g[bid * 64 + r];
        float4 wa = *(const float4*)&Wv_g[h8];
        float4 wb = *(const float4*)&Wv_g[h8 + 4];
        float4 ba = *(const float4*)&bv_g[h8];
        float4 bb = *(const float4*)&bv_g[h8 + 4];
        half8 v;
        v[0] = (_Float16)fmaxf(fmaf(mcv, wa.x, ba.x), 0.f);
        v[1] = (_Float16)fmaxf(fmaf(mcv, wa.y, ba.y), 0.f);
        v[2] = (_Float16)fmaxf(fmaf(mcv, wa.z, ba.z), 0.f);
        v[3] = (_Float16)fmaxf(fmaf(mcv, wa.w, ba.w), 0.f);
        v[4] = (_Float16)fmaxf(fmaf(mcv, wb.x, bb.x), 0.f);
        v[5] = (_Float16)fmaxf(fmaf(mcv, wb.y, bb.y), 0.f);
        v[6] = (_Float16)fmaxf(fmaf(mcv, wb.z, bb.z), 0.f);
        v[7] = (_Float16)fmaxf(fmaf(mcv, wb.w, bb.w), 0.f);
        *(half8*)((char*)lds + L_AH * 4 + r * 128 + (((t & 7) ^ (r & 7)) << 4)) = v;
    }
    __syncthreads();   // drains WmT+W1 async too

    const int lr = ln & 15, lq = ln >> 4;

    // ---- phase-1 MFMA: d_p -> dpH ----
    {
        const int rt = wv & 3, ch = wv >> 2;
        f32x4 acc[2];
        acc[0] = (f32x4){0.f, 0.f, 0.f, 0.f};
        acc[1] = (f32x4){0.f, 0.f, 0.f, 0.f};
#pragma unroll
        for (int ks = 0; ks < 2; ++ks) {
            const int c8 = ks * 4 + lq;
            const int r = rt * 16 + lr;
            half8 af = *(half8*)((char*)lds + L_AH * 4 + r * 128 + ((c8 ^ (r & 7)) << 4));
#pragma unroll
            for (int cti = 0; cti < 2; ++cti) {
                const int col = (ch * 2 + cti) * 16 + lr;
                half8 bf = *(half8*)((char*)lds + L_WM * 4 + col * 128 + ((c8 ^ (col & 7)) << 4));
                acc[cti] = __builtin_amdgcn_mfma_f32_16x16x32_f16(af, bf, acc[cti], 0, 0, 0);
            }
        }
        // epilogue: rows r = rt*16+lq*4+reg = b*8+mv; pair-add over reg pairs
        const int bloc = rt * 2 + (lq >> 1);
#pragma unroll
        for (int pp = 0; pp < 2; ++pp) {
            const int p = (lq & 1) * 2 + pp;
            const float sv = oh_g[(bid * 8 + bloc) * 4 + p];
            const int csb = (sv > 0.5f) ? S_C1 : S_C0;
            const int row32 = p * 8 + bloc, sw = row32 & 7;
#pragma unroll
            for (int cti = 0; cti < 2; ++cti) {
                const int e = (ch * 2 + cti) * 16 + lr;
                const float cs = lds[csb + e];
                float d0 = fmaxf(acc[cti][2 * pp] + cs, 0.f);
                float d1 = fmaxf(acc[cti][2 * pp + 1] + cs, 0.f);
                *(_Float16*)((char*)lds + L_DPH * 4 + row32 * 128
                             + (((e >> 3) ^ sw) << 4) + (e & 7) * 2) = (_Float16)(d0 + d1);
            }
        }
    }
    __syncthreads();   // phase-1 LDS reads done; dpH visible

    // ---- issue W2 async into (dead) Ah/WmT region; lands before GEMM-2 ----
#pragma unroll
    for (int rr = 0; rr < 4; ++rr)
        GLOAD(WS_W2 * 4 + rr * 8192 + wv * 1024 + ln * 16, L_W2 * 4 + rr * 8192 + wv * 1024);

    const int rtb = (wv & 3) * 2;   // 2 row-tiles
    const int ctb = (wv >> 2) * 4;  // 4 col-tiles

    // ---- GEMM-1: Hd1 = relu(A2 @ Wd1 + bd1), A2 rows (p,q,b) from dpH ----
    {
        f32x4 acc1[2][4];
#pragma unroll
        for (int i = 0; i < 2; ++i)
#pragma unroll
            for (int j = 0; j < 4; ++j) acc1[i][j] = (f32x4){0.f, 0.f, 0.f, 0.f};

#pragma unroll
        for (int ks = 0; ks < 4; ++ks) {
            const int c16 = ks * 4 + lq;
            const int c8  = (ks & 1) * 4 + lq;
            half8 af[2], bf[4];
#pragma unroll
            for (int i = 0; i < 2; ++i) {
                const int r  = (rtb + i) * 16 + lr;
                const int pq = (ks < 2) ? (r >> 5) : ((r >> 3) & 3);
                const int row32 = pq * 8 + (r & 7);
                af[i] = *(half8*)((char*)lds + L_DPH * 4 + row32 * 128 + ((c8 ^ (r & 7)) << 4));
            }
#pragma unroll
            for (int j = 0; j < 4; ++j) {
                const int col = (ctb + j) * 16 + lr;
                bf[j] = *(half8*)((char*)lds + L_W1 * 4 + col * 256 + ((c16 ^ (col & 7)) << 4));
            }
#pragma unroll
            for (int i = 0; i < 2; ++i)
#pragma unroll
                for (int j = 0; j < 4; ++j)
                    acc1[i][j] = __builtin_amdgcn_mfma_f32_16x16x32_f16(af[i], bf[j], acc1[i][j], 0, 0, 0);
        }
        __syncthreads();   // all Wd1T reads done before A2 overlays it

        // epilogue: +bd1, relu, cvt f16, store A2 swizzled over L_W1
#pragma unroll
        for (int rt = 0; rt < 2; ++rt)
#pragma unroll
            for (int reg = 0; reg < 4; ++reg) {
                const int row = (rtb + rt) * 16 + lq * 4 + reg;
                const int sw  = row & 7;
#pragma unroll
                for (int ct = 0; ct < 4; ++ct) {
                    const int col = (ctb + ct) * 16 + lr;
                    float hval = fmaxf(acc1[rt][ct][reg] + lds[S_BD1 + col], 0.f);
                    *(_Float16*)((char*)lds + L_W1 * 4 + row * 256
                                 + (((col >> 3) ^ sw) << 4) + (col & 7) * 2) = (_Float16)hval;
                }
            }
    }
    __syncthreads();   // A2 visible; W2 async drained by barrier

    // ---- GEMM-2: A = A2 (L_W1), B = Wd2T (L_W2) ----
    f32x4 acc[2][4];
#pragma unroll
    for (int i = 0; i < 2; ++i)
#pragma unroll
        for (int j = 0; j < 4; ++j) acc[i][j] = (f32x4){0.f, 0.f, 0.f, 0.f};

#pragma unroll
    for (int ks = 0; ks < 4; ++ks) {
        const int c16 = ks * 4 + lq;
        half8 af[2], bf[4];
#pragma unroll
        for (int i = 0; i < 2; ++i) {
            const int r = (rtb + i) * 16 + lr;
            af[i] = *(half8*)((char*)lds + L_W1 * 4 + r * 256 + ((c16 ^ (r & 7)) << 4));
        }
#pragma unroll
        for (int j = 0; j < 4; ++j) {
            const int col = (ctb + j) * 16 + lr;
            bf[j] = *(half8*)((char*)lds + L_W2 * 4 + col * 256 + ((c16 ^ (col & 7)) << 4));
        }
#pragma unroll
        for (int i = 0; i < 2; ++i)
#pragma unroll
            for (int j = 0; j < 4; ++j)
                acc[i][j] = __builtin_amdgcn_mfma_f32_16x16x32_f16(af[i], bf[j], acc[i][j], 0, 0, 0);
    }

    // ---- epilogue: relu(+bd2) * wc_eff (global, L1-hot), reduce, store ----
    {
        float part[2][4];
#pragma unroll
        for (int rt = 0; rt < 2; ++rt)
#pragma unroll
            for (int ii = 0; ii < 4; ++ii) {
                const int row = (rtb + rt) * 16 + 4 * lq + ii;
                const float* wcr = &wsf[(row >> 3) * 128];
                float pr = 0.f;
#pragma unroll
                for (int ct = 0; ct < 4; ++ct) {
                    const int col = (ctb + ct) * 16 + lr;
                    pr = fmaf(fmaxf(acc[rt][ct][ii] + lds[S_BD2 + col], 0.f), wcr[col], pr);
                }
                part[rt][ii] = pr;
            }
#pragma unroll
        for (int off = 1; off < 16; off <<= 1) {
#pragma unroll
            for (int rt = 0; rt < 2; ++rt)
#pragma unroll
                for (int ii = 0; ii < 4; ++ii)
                    part[rt][ii] += __shfl_xor(part[rt][ii], off, 64);
        }
        if (lr < 8) {
            const int rt = lr >> 2, ii = lr & 3;
            const int row = (rtb + rt) * 16 + 4 * lq + ii;
            lds[S_SP + (wv >> 2) * 128 + row] = part[rt][ii];
        }
    }
    __syncthreads();

    if (t < 32) {
        const float bcv = bc_g[0];
        float o = 0.f;
#pragma unroll
        for (int d = 0; d < 4; ++d) {
            const int r = t * 4 + d;
            o += fmaxf(lds[S_SP + r] + lds[S_SP + 128 + r] + bcv, 0.f);
        }
        const int p_ = t >> 3, q_ = (t >> 1) & 3;
        out[p_ * 32768 + q_ * 8192 + bid * 2 + (t & 1)] = o;
    }
}

extern "C" void kernel_launch(void* const* d_in, const int* in_sizes, int n_in,
                              void* d_out, int out_size, void* d_ws, size_t ws_size,
                              hipStream_t stream) {
    (void)in_sizes; (void)n_in; (void)out_size; (void)ws_size;
    const float* mc  = (const float*)d_in[0];
    const float* oh  = (const float*)d_in[1];
    const float* Wv  = (const float*)d_in[2];
    const float* bv  = (const float*)d_in[3];
    const float* Ws  = (const float*)d_in[4];
    const float* bs  = (const float*)d_in[5];
    const float* Wm  = (const float*)d_in[6];
    const float* bm  = (const float*)d_in[7];
    const float* rel = (const float*)d_in[8];
    const float* Wd1 = (const float*)d_in[9];
    const float* bd1 = (const float*)d_in[10];
    const float* Wd2 = (const float*)d_in[11];
    const float* bd2 = (const float*)d_in[12];
    const float* Wr1 = (const float*)d_in[13];
    const float* br1 = (const float*)d_in[14];
    const float* Wr2 = (const float*)d_in[15];
    const float* br2 = (const float*)d_in[16];
    const float* Wc  = (const float*)d_in[17];
    const float* bc  = (const float*)d_in[18];
    float* wsf = (float*)d_ws;
    float* out = (float*)d_out;

    hipLaunchKernelGGL(frap_setup, dim3(20), dim3(128), 0, stream,
                       Ws, bs, Wm, bm, rel, Wr1, br1, Wr2, br2, Wc, Wd1, Wd2, wsf);
    hipLaunchKernelGGL(frap_main, dim3(NBLK), dim3(NT), LDS_FLOATS * 4, stream,
                       mc, oh, Wv, bv, bd1, bd2, bc, wsf, out);
}

// Round 5
// 132.681 us; speedup vs baseline: 6.7950x; 1.0224x over previous
//
#include <hip/hip_runtime.h>

#define NT   512
#define NBLK 4096   // B/8

typedef _Float16 half8 __attribute__((ext_vector_type(8)));
typedef float    f32x4 __attribute__((ext_vector_type(4)));

// ---- LDS float offsets (38.4 KB -> 4 blocks/CU) ----
#define L_A2   0          // 8192 f: A2 f16 swz [128][256B]; Ah [64][128B] overlays early
#define L_AH   0
#define L_DPH  8192       // 1024 f: dpH f16 swz [32][128B]; S_SP overlays late
#define S_SP   8192       // 256 f
#define S_BD1  9216       // 128
#define S_BD2  9344       // 128
#define S_C0   9472       // 64
#define S_C1   9536       // 64
#define LDS_FLOATS 9600   // 38400 B

// ---- ws float offsets ----
#define WS_CS   2048    // c0/c1 (128 f)
#define WS_W2F  2304    // Wd2 B-fragments f16 (8192 f = 32KB), fragment-major
#define WS_W1F  10496   // Wd1 B-fragments f16 (8192 f)
#define WS_WMF  18688   // Wm  B-fragments f16 (2048 f = 8KB)

__global__ void frap_setup(const float* __restrict__ Ws0, const float* __restrict__ bs,
                           const float* __restrict__ Wm,  const float* __restrict__ bm,
                           const float* __restrict__ rel, const float* __restrict__ Wr1,
                           const float* __restrict__ br1, const float* __restrict__ Wr2,
                           const float* __restrict__ br2, const float* __restrict__ Wc,
                           const float* __restrict__ Wd1, const float* __restrict__ Wd2,
                           float* __restrict__ wsf)
{
    __shared__ float hr1[128];
    const int t = threadIdx.x;  // 128 threads
    if (blockIdx.x == 16) {
        const int s = t >> 6, e = t & 63;
        float acc = bm[e];
        for (int h = 0; h < 64; ++h) {
            float hs = fmaxf((s ? Ws0[h] : 0.0f) + bs[h], 0.0f);
            acc = fmaf(hs, Wm[(64 + h) * 64 + e], acc);
        }
        wsf[WS_CS + s * 64 + e] = acc;
    } else if (blockIdx.x == 17 || blockIdx.x == 18) {
        // B-fragments of W[128k][128col], fragment-major:
        // frag f = (tile*4+ks)*64 + lane ; 8 halves kk: W[(ks*4+(l>>4))*8+kk][tile*16+(l&15)]
        const float* Wsrc = (blockIdx.x == 17) ? Wd2 : Wd1;
        const int ofs = (blockIdx.x == 17) ? WS_W2F : WS_W1F;
        for (int f = t; f < 2048; f += 128) {
            const int l = f & 63, ks = (f >> 6) & 3, tile = f >> 8;
            const int kbase = (ks * 4 + (l >> 4)) * 8, col = tile * 16 + (l & 15);
            half8 v;
#pragma unroll
            for (int kk = 0; kk < 8; ++kk)
                v[kk] = (_Float16)Wsrc[(kbase + kk) * 128 + col];
            *(half8*)((char*)wsf + ofs * 4 + f * 16) = v;
        }
    } else if (blockIdx.x == 19) {
        // Wm_top[64k][64col] fragments: f = (tile*2+ks)*64 + lane, tile 0..3, ks 0..1
        for (int f = t; f < 512; f += 128) {
            const int l = f & 63, ks = (f >> 6) & 1, tile = f >> 7;
            const int kbase = (ks * 4 + (l >> 4)) * 8, col = tile * 16 + (l & 15);
            half8 v;
#pragma unroll
            for (int kk = 0; kk < 8; ++kk)
                v[kk] = (_Float16)Wm[(kbase + kk) * 64 + col];
            *(half8*)((char*)wsf + WS_WMF * 4 + f * 16) = v;
        }
    } else {
        const int pair = blockIdx.x;  // p*4+q
        float a = br1[t];
        for (int r = 0; r < 32; ++r) a = fmaf(rel[pair * 32 + r], Wr1[r * 128 + t], a);
        hr1[t] = fmaxf(a, 0.0f);
        __syncthreads();
        float a2 = br2[t];
        for (int j = 0; j < 128; ++j) a2 = fmaf(hr1[j], Wr2[j * 128 + t], a2);
        wsf[pair * 128 + t] = fmaxf(a2, 0.0f) * Wc[t];  // wc_eff
    }
}

__global__ __launch_bounds__(NT, 8)
void frap_main(const float* __restrict__ mc_g, const float* __restrict__ oh_g,
               const float* __restrict__ Wv_g, const float* __restrict__ bv_g,
               const float* __restrict__ bd1_g, const float* __restrict__ bd2_g,
               const float* __restrict__ bc_g,
               const float* __restrict__ wsf, float* __restrict__ out)
{
    extern __shared__ float lds[];
    const int t = threadIdx.x;
    const int wv = t >> 6, ln = t & 63;
    const int bid = blockIdx.x;

    // ---- consts ----
    if (t < 128) lds[S_BD1 + t] = bd1_g[t];
    else if (t < 256) lds[S_BD2 + (t - 128)] = bd2_g[t - 128];
    else if (t < 384) lds[S_C0 + (t - 256)] = wsf[WS_CS + (t - 256)];

    // ---- Ah[r=b*8+mv][64h] = relu(mc*Wv+bv) f16 swz ----
    {
        const int r = t >> 3, h8 = (t & 7) * 8;
        const float mcv = mc_g[bid * 64 + r];
        float4 wa = *(const float4*)&Wv_g[h8];
        float4 wb = *(const float4*)&Wv_g[h8 + 4];
        float4 ba = *(const float4*)&bv_g[h8];
        float4 bb = *(const float4*)&bv_g[h8 + 4];
        half8 v;
        v[0] = (_Float16)fmaxf(fmaf(mcv, wa.x, ba.x), 0.f);
        v[1] = (_Float16)fmaxf(fmaf(mcv, wa.y, ba.y), 0.f);
        v[2] = (_Float16)fmaxf(fmaf(mcv, wa.z, ba.z), 0.f);
        v[3] = (_Float16)fmaxf(fmaf(mcv, wa.w, ba.w), 0.f);
        v[4] = (_Float16)fmaxf(fmaf(mcv, wb.x, bb.x), 0.f);
        v[5] = (_Float16)fmaxf(fmaf(mcv, wb.y, bb.y), 0.f);
        v[6] = (_Float16)fmaxf(fmaf(mcv, wb.z, bb.z), 0.f);
        v[7] = (_Float16)fmaxf(fmaf(mcv, wb.w, bb.w), 0.f);
        *(half8*)((char*)lds + L_AH * 4 + r * 128 + (((t & 7) ^ (r & 7)) << 4)) = v;
    }
    __syncthreads();

    const int lr = ln & 15, lq = ln >> 4;

    // ---- phase-1 MFMA: d_p -> dpH (B-frags from global WmF) ----
    {
        const int rt = wv & 3, ch = wv >> 2;
        f32x4 acc[2];
        acc[0] = (f32x4){0.f, 0.f, 0.f, 0.f};
        acc[1] = (f32x4){0.f, 0.f, 0.f, 0.f};
#pragma unroll
        for (int ks = 0; ks < 2; ++ks) {
            const int c8 = ks * 4 + lq;
            const int r = rt * 16 + lr;
            half8 af = *(half8*)((char*)lds + L_AH * 4 + r * 128 + ((c8 ^ (r & 7)) << 4));
#pragma unroll
            for (int cti = 0; cti < 2; ++cti) {
                const int tile = ch * 2 + cti;
                half8 bf = *(const half8*)((const char*)wsf + WS_WMF * 4
                                           + ((tile * 2 + ks) * 64 + ln) * 16);
                acc[cti] = __builtin_amdgcn_mfma_f32_16x16x32_f16(af, bf, acc[cti], 0, 0, 0);
            }
        }
        // epilogue: rows r = rt*16+lq*4+reg = b*8+mv; pair-add over reg pairs
        const int bloc = rt * 2 + (lq >> 1);
#pragma unroll
        for (int pp = 0; pp < 2; ++pp) {
            const int p = (lq & 1) * 2 + pp;
            const float sv = oh_g[(bid * 8 + bloc) * 4 + p];
            const int csb = (sv > 0.5f) ? S_C1 : S_C0;
            const int row32 = p * 8 + bloc, sw = row32 & 7;
#pragma unroll
            for (int cti = 0; cti < 2; ++cti) {
                const int e = (ch * 2 + cti) * 16 + lr;
                const float cs = lds[csb + e];
                float d0 = fmaxf(acc[cti][2 * pp] + cs, 0.f);
                float d1 = fmaxf(acc[cti][2 * pp + 1] + cs, 0.f);
                *(_Float16*)((char*)lds + L_DPH * 4 + row32 * 128
                             + (((e >> 3) ^ sw) << 4) + (e & 7) * 2) = (_Float16)(d0 + d1);
            }
        }
    }
    __syncthreads();   // dpH visible; Ah reads done (A2 may overwrite)

    const int rtb = (wv & 3) * 2;   // 2 row-tiles
    const int ctb = (wv >> 2) * 4;  // 4 col-tiles

    // ---- GEMM-1: Hd1 = relu(A2in @ Wd1 + bd1); B-frags from global W1F ----
    {
        f32x4 acc1[2][4];
#pragma unroll
        for (int i = 0; i < 2; ++i)
#pragma unroll
            for (int j = 0; j < 4; ++j) acc1[i][j] = (f32x4){0.f, 0.f, 0.f, 0.f};

#pragma unroll
        for (int ks = 0; ks < 4; ++ks) {
            const int c8 = (ks & 1) * 4 + lq;
            half8 af[2], bf[4];
#pragma unroll
            for (int i = 0; i < 2; ++i) {
                const int r  = (rtb + i) * 16 + lr;
                const int pq = (ks < 2) ? (r >> 5) : ((r >> 3) & 3);
                const int row32 = pq * 8 + (r & 7);
                af[i] = *(half8*)((char*)lds + L_DPH * 4 + row32 * 128 + ((c8 ^ (r & 7)) << 4));
            }
#pragma unroll
            for (int j = 0; j < 4; ++j)
                bf[j] = *(const half8*)((const char*)wsf + WS_W1F * 4
                                        + (((ctb + j) * 4 + ks) * 64 + ln) * 16);
#pragma unroll
            for (int i = 0; i < 2; ++i)
#pragma unroll
                for (int j = 0; j < 4; ++j)
                    acc1[i][j] = __builtin_amdgcn_mfma_f32_16x16x32_f16(af[i], bf[j], acc1[i][j], 0, 0, 0);
        }
        __syncthreads();   // dpH reads done before A2 store (A2 is separate region, but Ah gone anyway)

        // epilogue: +bd1, relu, cvt f16, store A2 swizzled
#pragma unroll
        for (int rt = 0; rt < 2; ++rt)
#pragma unroll
            for (int reg = 0; reg < 4; ++reg) {
                const int row = (rtb + rt) * 16 + lq * 4 + reg;
                const int sw  = row & 7;
#pragma unroll
                for (int ct = 0; ct < 4; ++ct) {
                    const int col = (ctb + ct) * 16 + lr;
                    float hval = fmaxf(acc1[rt][ct][reg] + lds[S_BD1 + col], 0.f);
                    *(_Float16*)((char*)lds + L_A2 * 4 + row * 256
                                 + (((col >> 3) ^ sw) << 4) + (col & 7) * 2) = (_Float16)hval;
                }
            }
    }
    __syncthreads();   // A2 visible

    // ---- GEMM-2: A = A2 (LDS), B-frags from global W2F ----
    f32x4 acc[2][4];
#pragma unroll
    for (int i = 0; i < 2; ++i)
#pragma unroll
        for (int j = 0; j < 4; ++j) acc[i][j] = (f32x4){0.f, 0.f, 0.f, 0.f};

#pragma unroll
    for (int ks = 0; ks < 4; ++ks) {
        const int c16 = ks * 4 + lq;
        half8 af[2], bf[4];
#pragma unroll
        for (int i = 0; i < 2; ++i) {
            const int r = (rtb + i) * 16 + lr;
            af[i] = *(half8*)((char*)lds + L_A2 * 4 + r * 256 + ((c16 ^ (r & 7)) << 4));
        }
#pragma unroll
        for (int j = 0; j < 4; ++j)
            bf[j] = *(const half8*)((const char*)wsf + WS_W2F * 4
                                    + (((ctb + j) * 4 + ks) * 64 + ln) * 16);
#pragma unroll
        for (int i = 0; i < 2; ++i)
#pragma unroll
            for (int j = 0; j < 4; ++j)
                acc[i][j] = __builtin_amdgcn_mfma_f32_16x16x32_f16(af[i], bf[j], acc[i][j], 0, 0, 0);
    }

    // ---- epilogue: relu(+bd2) * wc_eff (global, L1-hot), reduce, store ----
    {
        float part[2][4];
#pragma unroll
        for (int rt = 0; rt < 2; ++rt)
#pragma unroll
            for (int ii = 0; ii < 4; ++ii) {
                const int row = (rtb + rt) * 16 + 4 * lq + ii;
                const float* wcr = &wsf[(row >> 3) * 128];
                float pr = 0.f;
#pragma unroll
                for (int ct = 0; ct < 4; ++ct) {
                    const int col = (ctb + ct) * 16 + lr;
                    pr = fmaf(fmaxf(acc[rt][ct][ii] + lds[S_BD2 + col], 0.f), wcr[col], pr);
                }
                part[rt][ii] = pr;
            }
#pragma unroll
        for (int off = 1; off < 16; off <<= 1) {
#pragma unroll
            for (int rt = 0; rt < 2; ++rt)
#pragma unroll
                for (int ii = 0; ii < 4; ++ii)
                    part[rt][ii] += __shfl_xor(part[rt][ii], off, 64);
        }
        if (lr < 8) {
            const int rt = lr >> 2, ii = lr & 3;
            const int row = (rtb + rt) * 16 + 4 * lq + ii;
            lds[S_SP + (wv >> 2) * 128 + row] = part[rt][ii];
        }
    }
    __syncthreads();

    if (t < 32) {
        const float bcv = bc_g[0];
        float o = 0.f;
#pragma unroll
        for (int d = 0; d < 4; ++d) {
            const int r = t * 4 + d;
            o += fmaxf(lds[S_SP + r] + lds[S_SP + 128 + r] + bcv, 0.f);
        }
        const int p_ = t >> 3, q_ = (t >> 1) & 3;
        out[p_ * 32768 + q_ * 8192 + bid * 2 + (t & 1)] = o;
    }
}

extern "C" void kernel_launch(void* const* d_in, const int* in_sizes, int n_in,
                              void* d_out, int out_size, void* d_ws, size_t ws_size,
                              hipStream_t stream) {
    (void)in_sizes; (void)n_in; (void)out_size; (void)ws_size;
    const float* mc  = (const float*)d_in[0];
    const float* oh  = (const float*)d_in[1];
    const float* Wv  = (const float*)d_in[2];
    const float* bv  = (const float*)d_in[3];
    const float* Ws  = (const float*)d_in[4];
    const float* bs  = (const float*)d_in[5];
    const float* Wm  = (const float*)d_in[6];
    const float* bm  = (const float*)d_in[7];
    const float* rel = (const float*)d_in[8];
    const float* Wd1 = (const float*)d_in[9];
    const float* bd1 = (const float*)d_in[10];
    const float* Wd2 = (const float*)d_in[11];
    const float* bd2 = (const float*)d_in[12];
    const float* Wr1 = (const float*)d_in[13];
    const float* br1 = (const float*)d_in[14];
    const float* Wr2 = (const float*)d_in[15];
    const float* br2 = (const float*)d_in[16];
    const float* Wc  = (const float*)d_in[17];
    const float* bc  = (const float*)d_in[18];
    float* wsf = (float*)d_ws;
    float* out = (float*)d_out;

    hipLaunchKernelGGL(frap_setup, dim3(20), dim3(128), 0, stream,
                       Ws, bs, Wm, bm, rel, Wr1, br1, Wr2, br2, Wc, Wd1, Wd2, wsf);
    hipLaunchKernelGGL(frap_main, dim3(NBLK), dim3(NT), LDS_FLOATS * 4, stream,
                       mc, oh, Wv, bv, bd1, bd2, bc, wsf, out);
}

// Round 6
// 83.892 us; speedup vs baseline: 10.7467x; 1.5816x over previous
//
#include <hip/hip_runtime.h>

#define NT   512
#define NBLK 4096   // B/8

typedef _Float16 half8 __attribute__((ext_vector_type(8)));
typedef float    f32x4 __attribute__((ext_vector_type(4)));

// ---- LDS float offsets (38.4 KB -> 3 blocks/CU at 6 waves/SIMD) ----
#define L_A2   0          // 8192 f: A2 f16 swz [128][256B]; Ah [64][128B] overlays early
#define L_AH   0
#define L_DPH  8192       // 1024 f: dpH f16 swz [32][128B]; S_SP overlays late
#define S_SP   8192       // 256 f
#define S_BD1  9216       // 128
#define S_BD2  9344       // 128
#define S_C0   9472       // 64
#define S_C1   9536       // 64
#define LDS_FLOATS 9600   // 38400 B

// ---- ws float offsets ----
#define WS_CS   2048    // c0/c1 (128 f)
#define WS_W2F  2304    // Wd2 B-fragments f16 (8192 f = 32KB), fragment-major
#define WS_W1F  10496   // Wd1 B-fragments f16 (8192 f)
#define WS_WMF  18688   // Wm  B-fragments f16 (2048 f = 8KB)

__global__ void frap_setup(const float* __restrict__ Ws0, const float* __restrict__ bs,
                           const float* __restrict__ Wm,  const float* __restrict__ bm,
                           const float* __restrict__ rel, const float* __restrict__ Wr1,
                           const float* __restrict__ br1, const float* __restrict__ Wr2,
                           const float* __restrict__ br2, const float* __restrict__ Wc,
                           const float* __restrict__ Wd1, const float* __restrict__ Wd2,
                           float* __restrict__ wsf)
{
    __shared__ float hr1[128];
    const int t = threadIdx.x;  // 128 threads
    if (blockIdx.x == 16) {
        const int s = t >> 6, e = t & 63;
        float acc = bm[e];
        for (int h = 0; h < 64; ++h) {
            float hs = fmaxf((s ? Ws0[h] : 0.0f) + bs[h], 0.0f);
            acc = fmaf(hs, Wm[(64 + h) * 64 + e], acc);
        }
        wsf[WS_CS + s * 64 + e] = acc;
    } else if (blockIdx.x == 17 || blockIdx.x == 18) {
        // B-fragments of W[128k][128col], fragment-major:
        // frag f = (tile*4+ks)*64 + lane ; 8 halves kk: W[(ks*4+(l>>4))*8+kk][tile*16+(l&15)]
        const float* Wsrc = (blockIdx.x == 17) ? Wd2 : Wd1;
        const int ofs = (blockIdx.x == 17) ? WS_W2F : WS_W1F;
        for (int f = t; f < 2048; f += 128) {
            const int l = f & 63, ks = (f >> 6) & 3, tile = f >> 8;
            const int kbase = (ks * 4 + (l >> 4)) * 8, col = tile * 16 + (l & 15);
            half8 v;
#pragma unroll
            for (int kk = 0; kk < 8; ++kk)
                v[kk] = (_Float16)Wsrc[(kbase + kk) * 128 + col];
            *(half8*)((char*)wsf + ofs * 4 + f * 16) = v;
        }
    } else if (blockIdx.x == 19) {
        // Wm_top[64k][64col] fragments: f = (tile*2+ks)*64 + lane, tile 0..3, ks 0..1
        for (int f = t; f < 512; f += 128) {
            const int l = f & 63, ks = (f >> 6) & 1, tile = f >> 7;
            const int kbase = (ks * 4 + (l >> 4)) * 8, col = tile * 16 + (l & 15);
            half8 v;
#pragma unroll
            for (int kk = 0; kk < 8; ++kk)
                v[kk] = (_Float16)Wm[(kbase + kk) * 64 + col];
            *(half8*)((char*)wsf + WS_WMF * 4 + f * 16) = v;
        }
    } else {
        const int pair = blockIdx.x;  // p*4+q
        float a = br1[t];
        for (int r = 0; r < 32; ++r) a = fmaf(rel[pair * 32 + r], Wr1[r * 128 + t], a);
        hr1[t] = fmaxf(a, 0.0f);
        __syncthreads();
        float a2 = br2[t];
        for (int j = 0; j < 128; ++j) a2 = fmaf(hr1[j], Wr2[j * 128 + t], a2);
        wsf[pair * 128 + t] = fmaxf(a2, 0.0f) * Wc[t];  // wc_eff
    }
}

__global__ __launch_bounds__(NT, 6)
void frap_main(const float* __restrict__ mc_g, const float* __restrict__ oh_g,
               const float* __restrict__ Wv_g, const float* __restrict__ bv_g,
               const float* __restrict__ bd1_g, const float* __restrict__ bd2_g,
               const float* __restrict__ bc_g,
               const float* __restrict__ wsf, float* __restrict__ out)
{
    extern __shared__ float lds[];
    const int t = threadIdx.x;
    const int wv = t >> 6, ln = t & 63;
    const int bid = blockIdx.x;

    // ---- consts ----
    if (t < 128) lds[S_BD1 + t] = bd1_g[t];
    else if (t < 256) lds[S_BD2 + (t - 128)] = bd2_g[t - 128];
    else if (t < 384) lds[S_C0 + (t - 256)] = wsf[WS_CS + (t - 256)];

    // ---- Ah[r=b*8+mv][64h] = relu(mc*Wv+bv) f16 swz ----
    {
        const int r = t >> 3, h8 = (t & 7) * 8;
        const float mcv = mc_g[bid * 64 + r];
        float4 wa = *(const float4*)&Wv_g[h8];
        float4 wb = *(const float4*)&Wv_g[h8 + 4];
        float4 ba = *(const float4*)&bv_g[h8];
        float4 bb = *(const float4*)&bv_g[h8 + 4];
        half8 v;
        v[0] = (_Float16)fmaxf(fmaf(mcv, wa.x, ba.x), 0.f);
        v[1] = (_Float16)fmaxf(fmaf(mcv, wa.y, ba.y), 0.f);
        v[2] = (_Float16)fmaxf(fmaf(mcv, wa.z, ba.z), 0.f);
        v[3] = (_Float16)fmaxf(fmaf(mcv, wa.w, ba.w), 0.f);
        v[4] = (_Float16)fmaxf(fmaf(mcv, wb.x, bb.x), 0.f);
        v[5] = (_Float16)fmaxf(fmaf(mcv, wb.y, bb.y), 0.f);
        v[6] = (_Float16)fmaxf(fmaf(mcv, wb.z, bb.z), 0.f);
        v[7] = (_Float16)fmaxf(fmaf(mcv, wb.w, bb.w), 0.f);
        *(half8*)((char*)lds + L_AH * 4 + r * 128 + (((t & 7) ^ (r & 7)) << 4)) = v;
    }
    __syncthreads();

    const int lr = ln & 15, lq = ln >> 4;

    // ---- phase-1 MFMA: d_p -> dpH (B-frags from global WmF) ----
    {
        const int rt = wv & 3, ch = wv >> 2;
        f32x4 acc[2];
        acc[0] = (f32x4){0.f, 0.f, 0.f, 0.f};
        acc[1] = (f32x4){0.f, 0.f, 0.f, 0.f};
#pragma unroll
        for (int ks = 0; ks < 2; ++ks) {
            const int c8 = ks * 4 + lq;
            const int r = rt * 16 + lr;
            half8 af = *(half8*)((char*)lds + L_AH * 4 + r * 128 + ((c8 ^ (r & 7)) << 4));
#pragma unroll
            for (int cti = 0; cti < 2; ++cti) {
                const int tile = ch * 2 + cti;
                half8 bf = *(const half8*)((const char*)wsf + WS_WMF * 4
                                           + ((tile * 2 + ks) * 64 + ln) * 16);
                acc[cti] = __builtin_amdgcn_mfma_f32_16x16x32_f16(af, bf, acc[cti], 0, 0, 0);
            }
        }
        // epilogue: rows r = rt*16+lq*4+reg = b*8+mv; pair-add over reg pairs
        const int bloc = rt * 2 + (lq >> 1);
#pragma unroll
        for (int pp = 0; pp < 2; ++pp) {
            const int p = (lq & 1) * 2 + pp;
            const float sv = oh_g[(bid * 8 + bloc) * 4 + p];
            const int csb = (sv > 0.5f) ? S_C1 : S_C0;
            const int row32 = p * 8 + bloc, sw = row32 & 7;
#pragma unroll
            for (int cti = 0; cti < 2; ++cti) {
                const int e = (ch * 2 + cti) * 16 + lr;
                const float cs = lds[csb + e];
                float d0 = fmaxf(acc[cti][2 * pp] + cs, 0.f);
                float d1 = fmaxf(acc[cti][2 * pp + 1] + cs, 0.f);
                *(_Float16*)((char*)lds + L_DPH * 4 + row32 * 128
                             + (((e >> 3) ^ sw) << 4) + (e & 7) * 2) = (_Float16)(d0 + d1);
            }
        }
    }
    __syncthreads();   // dpH visible; Ah reads done (A2 may overwrite)

    const int rtb = (wv & 3) * 2;   // 2 row-tiles
    const int ctb = (wv >> 2) * 4;  // 4 col-tiles

    // ---- GEMM-1: Hd1 = relu(A2in @ Wd1 + bd1); B-frags from global W1F ----
    {
        f32x4 acc1[2][4];
#pragma unroll
        for (int i = 0; i < 2; ++i)
#pragma unroll
            for (int j = 0; j < 4; ++j) acc1[i][j] = (f32x4){0.f, 0.f, 0.f, 0.f};

#pragma unroll
        for (int ks = 0; ks < 4; ++ks) {
            const int c8 = (ks & 1) * 4 + lq;
            half8 af[2], bf[4];
#pragma unroll
            for (int i = 0; i < 2; ++i) {
                const int r  = (rtb + i) * 16 + lr;
                const int pq = (ks < 2) ? (r >> 5) : ((r >> 3) & 3);
                const int row32 = pq * 8 + (r & 7);
                af[i] = *(half8*)((char*)lds + L_DPH * 4 + row32 * 128 + ((c8 ^ (r & 7)) << 4));
            }
#pragma unroll
            for (int j = 0; j < 4; ++j)
                bf[j] = *(const half8*)((const char*)wsf + WS_W1F * 4
                                        + (((ctb + j) * 4 + ks) * 64 + ln) * 16);
#pragma unroll
            for (int i = 0; i < 2; ++i)
#pragma unroll
                for (int j = 0; j < 4; ++j)
                    acc1[i][j] = __builtin_amdgcn_mfma_f32_16x16x32_f16(af[i], bf[j], acc1[i][j], 0, 0, 0);
        }
        __syncthreads();   // dpH reads done before A2 store

        // epilogue: +bd1, relu, cvt f16, store A2 swizzled
#pragma unroll
        for (int rt = 0; rt < 2; ++rt)
#pragma unroll
            for (int reg = 0; reg < 4; ++reg) {
                const int row = (rtb + rt) * 16 + lq * 4 + reg;
                const int sw  = row & 7;
#pragma unroll
                for (int ct = 0; ct < 4; ++ct) {
                    const int col = (ctb + ct) * 16 + lr;
                    float hval = fmaxf(acc1[rt][ct][reg] + lds[S_BD1 + col], 0.f);
                    *(_Float16*)((char*)lds + L_A2 * 4 + row * 256
                                 + (((col >> 3) ^ sw) << 4) + (col & 7) * 2) = (_Float16)hval;
                }
            }
    }
    __syncthreads();   // A2 visible

    // ---- GEMM-2: A = A2 (LDS), B-frags from global W2F ----
    f32x4 acc[2][4];
#pragma unroll
    for (int i = 0; i < 2; ++i)
#pragma unroll
        for (int j = 0; j < 4; ++j) acc[i][j] = (f32x4){0.f, 0.f, 0.f, 0.f};

#pragma unroll
    for (int ks = 0; ks < 4; ++ks) {
        const int c16 = ks * 4 + lq;
        half8 af[2], bf[4];
#pragma unroll
        for (int i = 0; i < 2; ++i) {
            const int r = (rtb + i) * 16 + lr;
            af[i] = *(half8*)((char*)lds + L_A2 * 4 + r * 256 + ((c16 ^ (r & 7)) << 4));
        }
#pragma unroll
        for (int j = 0; j < 4; ++j)
            bf[j] = *(const half8*)((const char*)wsf + WS_W2F * 4
                                    + (((ctb + j) * 4 + ks) * 64 + ln) * 16);
#pragma unroll
        for (int i = 0; i < 2; ++i)
#pragma unroll
            for (int j = 0; j < 4; ++j)
                acc[i][j] = __builtin_amdgcn_mfma_f32_16x16x32_f16(af[i], bf[j], acc[i][j], 0, 0, 0);
    }

    // ---- epilogue: relu(+bd2) * wc_eff (global, L1-hot), reduce, store ----
    {
        float part[2][4];
#pragma unroll
        for (int rt = 0; rt < 2; ++rt)
#pragma unroll
            for (int ii = 0; ii < 4; ++ii) {
                const int row = (rtb + rt) * 16 + 4 * lq + ii;
                const float* wcr = &wsf[(row >> 3) * 128];
                float pr = 0.f;
#pragma unroll
                for (int ct = 0; ct < 4; ++ct) {
                    const int col = (ctb + ct) * 16 + lr;
                    pr = fmaf(fmaxf(acc[rt][ct][ii] + lds[S_BD2 + col], 0.f), wcr[col], pr);
                }
                part[rt][ii] = pr;
            }
#pragma unroll
        for (int off = 1; off < 16; off <<= 1) {
#pragma unroll
            for (int rt = 0; rt < 2; ++rt)
#pragma unroll
                for (int ii = 0; ii < 4; ++ii)
                    part[rt][ii] += __shfl_xor(part[rt][ii], off, 64);
        }
        if (lr < 8) {
            const int rt = lr >> 2, ii = lr & 3;
            const int row = (rtb + rt) * 16 + 4 * lq + ii;
            lds[S_SP + (wv >> 2) * 128 + row] = part[rt][ii];
        }
    }
    __syncthreads();

    if (t < 32) {
        const float bcv = bc_g[0];
        float o = 0.f;
#pragma unroll
        for (int d = 0; d < 4; ++d) {
            const int r = t * 4 + d;
            o += fmaxf(lds[S_SP + r] + lds[S_SP + 128 + r] + bcv, 0.f);
        }
        const int p_ = t >> 3, q_ = (t >> 1) & 3;
        out[p_ * 32768 + q_ * 8192 + bid * 2 + (t & 1)] = o;
    }
}

extern "C" void kernel_launch(void* const* d_in, const int* in_sizes, int n_in,
                              void* d_out, int out_size, void* d_ws, size_t ws_size,
                              hipStream_t stream) {
    (void)in_sizes; (void)n_in; (void)out_size; (void)ws_size;
    const float* mc  = (const float*)d_in[0];
    const float* oh  = (const float*)d_in[1];
    const float* Wv  = (const float*)d_in[2];
    const float* bv  = (const float*)d_in[3];
    const float* Ws  = (const float*)d_in[4];
    const float* bs  = (const float*)d_in[5];
    const float* Wm  = (const float*)d_in[6];
    const float* bm  = (const float*)d_in[7];
    const float* rel = (const float*)d_in[8];
    const float* Wd1 = (const float*)d_in[9];
    const float* bd1 = (const float*)d_in[10];
    const float* Wd2 = (const float*)d_in[11];
    const float* bd2 = (const float*)d_in[12];
    const float* Wr1 = (const float*)d_in[13];
    const float* br1 = (const float*)d_in[14];
    const float* Wr2 = (const float*)d_in[15];
    const float* br2 = (const float*)d_in[16];
    const float* Wc  = (const float*)d_in[17];
    const float* bc  = (const float*)d_in[18];
    float* wsf = (float*)d_ws;
    float* out = (float*)d_out;

    hipLaunchKernelGGL(frap_setup, dim3(20), dim3(128), 0, stream,
                       Ws, bs, Wm, bm, rel, Wr1, br1, Wr2, br2, Wc, Wd1, Wd2, wsf);
    hipLaunchKernelGGL(frap_main, dim3(NBLK), dim3(NT), LDS_FLOATS * 4, stream,
                       mc, oh, Wv, bv, bd1, bd2, bc, wsf, out);
}